// Round 3
// baseline (287.677 us; speedup 1.0000x reference)
//
#include <hip/hip_runtime.h>
#include <hip/hip_cooperative_groups.h>
#include <math.h>

namespace cg = cooperative_groups;

#define BB 16
#define NN 65536
#define DD 24
#define KK 512
// fused kernel geometry
#define FBLK 256           // blocks (1/CU co-residency required; LDS bound gives 2/CU)
#define FTPB 512           // threads per block (8 waves)
#define FCPB 16            // fused chunk-sets per batch (FBLK/BB)
#define FHPB (NN / FCPB)   // 4096 hits per block
// legacy (fallback) geometry
#define CH 64
#define HPB (NN / CH)
#define TPB 256
#define RPB 8

__device__ __forceinline__ float fixnum(float v) {
  return __builtin_isfinite(v) ? v : 0.0f;  // nan_to_num(nan=0, posinf=0, neginf=0)
}

// ---- 512-thread block sum; returns total in ALL threads ----
__device__ __forceinline__ float blockReduceSum8(float v, float* sbuf) {
  __syncthreads();
  #pragma unroll
  for (int off = 32; off > 0; off >>= 1) v += __shfl_down(v, off, 64);
  int wid = threadIdx.x >> 6, lane = threadIdx.x & 63;
  if (lane == 0) sbuf[wid] = v;
  __syncthreads();
  float s = 0.f;
  #pragma unroll
  for (int i = 0; i < 8; ++i) s += sbuf[i];
  return s;
}

// ---- 256-thread block sum (fallback kernels) ----
__device__ __forceinline__ float blockReduceSum(float v, float* sbuf) {
  __syncthreads();
  #pragma unroll
  for (int off = 32; off > 0; off >>= 1) v += __shfl_down(v, off, 64);
  int wid = threadIdx.x >> 6, lane = threadIdx.x & 63;
  if (lane == 0) sbuf[wid] = v;
  __syncthreads();
  return sbuf[0] + sbuf[1] + sbuf[2] + sbuf[3];
}

// ================= FUSED cooperative kernel: all 4 phases =================
__global__ __launch_bounds__(FTPB, 2) void kfused(
    const float* __restrict__ beta, const float* __restrict__ embed,
    const int* __restrict__ sid, const int* __restrict__ iscp,
    float* __restrict__ cnt_p, float* __restrict__ den_p,
    float* __restrict__ cpc_p, float* __restrict__ cpl_p,
    int* __restrict__ first_p, float* __restrict__ marg_p,
    float* __restrict__ seg_cnt, float* __restrict__ loss_v,
    float* __restrict__ valid_f, float* __restrict__ has_cp_f,
    float* __restrict__ cpc_tot, float* __restrict__ cp_emb,
    float* __restrict__ d2_acc, float* __restrict__ rep_acc,
    float* __restrict__ out)
{
  // LDS: s_ce is reused by phase1 as the 5 partial-accumulator arrays.
  __shared__ __align__(16) float s_ce[KK * DD];   // 49152 B
  __shared__ float s_tile[128 * 25];              // 12800 B
  __shared__ float s_d2[KK];                      // 2048 B
  __shared__ float sred[8];
  __shared__ float s_b[BB][5];

  cg::grid_group grid = cg::this_grid();
  int blk = blockIdx.x, t = threadIdx.x;
  int b = blk >> 4, qc = blk & 15;                // batch, chunk-set

  // ---------------- Phase 1: beta/segment scan (4096 hits/block) ----------
  {
    float* s_cnt = s_ce;            // [KK]
    float* s_den = s_ce + KK;       // [KK]
    float* s_cpc = s_ce + 2 * KK;   // [KK]
    float* s_cpl = s_ce + 3 * KK;   // [KK]
    int*   s_first = (int*)(s_ce + 4 * KK);  // [KK]
    if (t < KK) {
      s_cnt[t] = 0.f; s_den[t] = 0.f; s_cpc[t] = 0.f; s_cpl[t] = 0.f;
      s_first[t] = NN;
    }
    __syncthreads();
    int h0 = qc * FHPB + t * 8;                  // 8 consecutive hits per thread
    size_t g0 = (size_t)b * NN + h0;
    float4 bv0 = *(const float4*)(beta + g0);
    float4 bv1 = *(const float4*)(beta + g0 + 4);
    int4   sv0 = *(const int4*)(sid + g0);
    int4   sv1 = *(const int4*)(sid + g0 + 4);
    int4   cv0 = *(const int4*)(iscp + g0);
    int4   cv1 = *(const int4*)(iscp + g0 + 4);
    float bs[8] = {bv0.x, bv0.y, bv0.z, bv0.w, bv1.x, bv1.y, bv1.z, bv1.w};
    int   ss[8] = {sv0.x, sv0.y, sv0.z, sv0.w, sv1.x, sv1.y, sv1.z, sv1.w};
    int   cs[8] = {cv0.x, cv0.y, cv0.z, cv0.w, cv1.x, cv1.y, cv1.z, cv1.w};
    float pm = 0.f, nm = 0.f;
    #pragma unroll
    for (int j = 0; j < 8; ++j) {
      float bc = fminf(fmaxf(fixnum(bs[j]), -20.f), 20.f);
      float logit = bc * (1.0f / 0.7f);          // TAU
      int s = ss[j];
      atomicAdd(&s_cnt[s], 1.0f);
      atomicAdd(&s_den[s], __expf(logit));       // max-free denom, no overflow
      float prob = 1.0f / (1.0f + __expf(-bc));
      if (cs[j] == 1) {
        atomicAdd(&s_cpc[s], 1.0f);
        atomicAdd(&s_cpl[s], logit);
        atomicMin(&s_first[s], h0 + j);
        pm += fmaxf(0.7f - prob, 0.f);           // THRESHOLD+MARGIN
      } else {
        nm += fmaxf(prob - 0.3f, 0.f);           // THRESHOLD-MARGIN
      }
    }
    float pms = blockReduceSum8(pm, sred);
    float nms = blockReduceSum8(nm, sred);
    if (t == 0) { marg_p[2 * blk] = pms; marg_p[2 * blk + 1] = nms; }
    __syncthreads();
    size_t base = (size_t)blk * KK;              // blk == b*16+qc
    if (t < KK) {
      cnt_p[base + t] = s_cnt[t]; den_p[base + t] = s_den[t];
      cpc_p[base + t] = s_cpc[t]; cpl_p[base + t] = s_cpl[t];
      first_p[base + t] = s_first[t];
    }
  }
  grid.sync();   // ---- SYNC1: partials + marg visible ----

  // ---------------- Phase 2: finalize per (b,k); blocks 0..15 -------------
  if (blk < BB) {
    int bb = blk, k = t;                         // 512 threads == 512 segments
    float cnt = 0.f, den = 0.f, cpc = 0.f, cpl = 0.f;
    int fc = NN;
    #pragma unroll 4
    for (int c = 0; c < FCPB; ++c) {
      size_t base = ((size_t)bb * FCPB + c) * KK + k;
      cnt += cnt_p[base]; den += den_p[base];
      cpc += cpc_p[base]; cpl += cpl_p[base];
      fc = min(fc, first_p[base]);
    }
    int idx = bb * KK + k;
    bool present = cnt > 0.f;
    bool vinst = present && (cpc == 1.0f);
    float p = __expf(cpl) / fmaxf(den, 1e-30f);
    seg_cnt[idx] = cnt;
    cpc_tot[idx] = cpc;
    loss_v[idx] = vinst ? -__logf(p + 1e-9f) : 0.f;
    valid_f[idx] = vinst ? 1.f : 0.f;
    has_cp_f[idx] = ((fc < NN) && present) ? 1.f : 0.f;
    d2_acc[idx] = 0.f;
    if (blk == 0 && t < BB) rep_acc[t] = 0.f;
    int row = fc < NN ? fc : NN - 1;
    const float4* src = (const float4*)(embed + ((size_t)bb * NN + row) * DD);
    float4* dst = (float4*)(cp_emb + (size_t)idx * DD);
    #pragma unroll
    for (int q = 0; q < DD / 4; ++q) {
      float4 v = src[q];
      v.x = fixnum(v.x); v.y = fixnum(v.y); v.z = fixnum(v.z); v.w = fixnum(v.w);
      dst[q] = v;
    }
  }
  grid.sync();   // ---- SYNC2: cp_emb/has_cp/zeros visible ----

  // ---------------- Phase 3: attraction (4096 hits/block) + repulsion -----
  {
    // stage cp_emb[b] -> LDS (3072 float4 over 512 threads)
    const float4* ceg = (const float4*)(cp_emb + (size_t)b * KK * DD);
    float4* ces = (float4*)s_ce;
    #pragma unroll
    for (int i = 0; i < (KK * DD / 4) / FTPB; ++i)   // 6
      ces[t + i * FTPB] = ceg[t + i * FTPB];
    if (t < KK) s_d2[t] = 0.f;

    int hl = t >> 2, q = t & 3, d0 = q * 6;      // quad: 4 lanes x 6 dims/hit
    int rbase = hl * 25 + d0;
    int wI[3];
    #pragma unroll
    for (int j = 0; j < 3; ++j) {                // float2 pairs never straddle rows
      int f = 2 * (t + j * FTPB);                // 0..3070, even
      int h = f / 24;
      wI[j] = h * 25 + (f - h * 24);
    }
    size_t hit0 = (size_t)b * NN + (size_t)qc * FHPB;
    const float2* eb2 = (const float2*)(embed + hit0 * DD);
    const int* sidb = sid + hit0;

    float2 r[3];                                 // preload tile 0
    #pragma unroll
    for (int j = 0; j < 3; ++j) r[j] = eb2[t + j * FTPB];
    __syncthreads();                             // s_ce, s_d2 ready

    for (int tile = 0; tile < 32; ++tile) {      // 32 tiles x 128 hits
      #pragma unroll
      for (int j = 0; j < 3; ++j) {
        s_tile[wI[j]]     = fixnum(r[j].x);
        s_tile[wI[j] + 1] = fixnum(r[j].y);
      }
      __syncthreads();
      if (tile < 31) {
        const float2* nb = eb2 + (size_t)(tile + 1) * (128 * DD / 2);
        #pragma unroll
        for (int j = 0; j < 3; ++j) r[j] = nb[t + j * FTPB];
      }
      int s = sidb[tile * 128 + hl];
      int cbase = s * DD + d0;
      float d2 = 0.f;
      #pragma unroll
      for (int d = 0; d < 6; ++d) {
        float x = s_tile[rbase + d] - s_ce[cbase + d];
        d2 += x * x;
      }
      d2 += __shfl_xor(d2, 1, 64);
      d2 += __shfl_xor(d2, 2, 64);
      if (q == 0) atomicAdd(&s_d2[s], fminf(d2, 50.f));
      __syncthreads();
    }
    if (t < KK) atomicAdd(&d2_acc[b * KK + t], s_d2[t]);  // 16 adds/address

    // repulsion: rows qc*32..+32, col j0 = t (512 cols == 512 threads)
    int j0 = t;
    float cj[DD];
    const float4* cjp = (const float4*)(s_ce + j0 * DD);
    #pragma unroll
    for (int qq = 0; qq < DD / 4; ++qq) {
      float4 a = cjp[qq];
      cj[qq*4] = a.x; cj[qq*4+1] = a.y; cj[qq*4+2] = a.z; cj[qq*4+3] = a.w;
    }
    float m0 = has_cp_f[b * KK + j0];
    float acc = 0.f;
    #pragma unroll 4
    for (int ri = 0; ri < 32; ++ri) {
      int i2 = qc * 32 + ri;
      float mi = has_cp_f[b * KK + i2];          // uniform
      float d2r = 0.f;
      #pragma unroll
      for (int d = 0; d < DD; ++d) {
        float x = s_ce[i2 * DD + d] - cj[d];     // uniform -> LDS broadcast
        d2r += x * x;
      }
      acc += mi * m0 * __expf(-fminf(d2r, 50.f));
    }
    float tot = blockReduceSum8(acc, sred);
    if (t == 0) atomicAdd(&rep_acc[b], tot);
  }
  grid.sync();   // ---- SYNC3: d2_acc/rep_acc visible ----

  // ---------------- Phase 4: final combine (block 0) -----------------------
  if (blk == 0) {
    int w = t >> 6, l = t & 63;                  // 8 waves; each does 2 batches
    for (int bb = w; bb < BB; bb += 8) {
      float attr = 0.f, ce = 0.f, vcnt = 0.f, pcnt = 0.f, mcnt = 0.f;
      #pragma unroll
      for (int k = l; k < KK; k += 64) {
        int idx = bb * KK + k;
        float hc = has_cp_f[idx];
        attr += hc * (d2_acc[idx] / fmaxf(seg_cnt[idx], 1.f));
        ce   += loss_v[idx];
        vcnt += valid_f[idx];
        pcnt += cpc_tot[idx];
        mcnt += hc;
      }
      float pm = (l < FCPB) ? marg_p[2 * (bb * FCPB + l)] : 0.f;
      float nm = (l < FCPB) ? marg_p[2 * (bb * FCPB + l) + 1] : 0.f;
      #pragma unroll
      for (int off = 32; off > 0; off >>= 1) {
        attr += __shfl_down(attr, off, 64);
        ce   += __shfl_down(ce, off, 64);
        vcnt += __shfl_down(vcnt, off, 64);
        pcnt += __shfl_down(pcnt, off, 64);
        mcnt += __shfl_down(mcnt, off, 64);
        pm   += __shfl_down(pm, off, 64);
        nm   += __shfl_down(nm, off, 64);
      }
      if (l == 0) {
        float pos = pcnt, neg = (float)NN - pos;
        float slice_ce = ce / fmaxf(vcnt, 1.f);
        float beta_loss = slice_ce + 5.0f * (pm / fmaxf(pos, 1.f) + nm / fmaxf(neg, 1.f));
        float rep = rep_acc[bb] / fmaxf(mcnt * mcnt, 1.f);
        float repulsion = (mcnt > 1.f) ? 1.5f * rep : 0.f;
        float v = (pos >= 1.f && neg >= 1.f && vcnt > 0.f) ? 1.f : 0.f;
        s_b[bb][0] = (beta_loss + attr + repulsion) * v;
        s_b[bb][1] = beta_loss * v;
        s_b[bb][2] = attr * v;
        s_b[bb][3] = repulsion * v;
        s_b[bb][4] = v;
      }
    }
    __syncthreads();
    if (t == 0) {
      float s0 = 0.f, s1 = 0.f, s2 = 0.f, s3 = 0.f, cv = 0.f;
      #pragma unroll
      for (int i = 0; i < BB; ++i) {
        s0 += s_b[i][0]; s1 += s_b[i][1]; s2 += s_b[i][2]; s3 += s_b[i][3];
        cv += s_b[i][4];
      }
      float safe = fmaxf(cv, 1.f);
      bool ok = cv > 0.f;
      out[0] = ok ? s0 / safe : 0.f;
      out[1] = ok ? s1 / safe : 0.f;
      out[2] = ok ? s2 / safe : 0.f;
      out[3] = ok ? s3 / safe : 0.f;
    }
  }
}

// ================= Fallback path: round-1 four-kernel pipeline =============
__global__ __launch_bounds__(TPB) void k1_seg(
    const float* __restrict__ beta, const int* __restrict__ sid,
    const int* __restrict__ iscp,
    float* __restrict__ cnt_p, float* __restrict__ den_p,
    float* __restrict__ cpc_p, float* __restrict__ cpl_p,
    int* __restrict__ first_p, float* __restrict__ marg_p)
{
  __shared__ float s_cnt[KK], s_den[KK], s_cpc[KK], s_cpl[KK];
  __shared__ int   s_first[KK];
  __shared__ float sred[4];
  int b = blockIdx.x >> 6, c = blockIdx.x & 63, t = threadIdx.x;
  for (int k = t; k < KK; k += TPB) {
    s_cnt[k] = 0.f; s_den[k] = 0.f; s_cpc[k] = 0.f; s_cpl[k] = 0.f; s_first[k] = NN;
  }
  __syncthreads();
  int h0 = c * HPB + t * 4;
  size_t g0 = (size_t)b * NN + h0;
  float4 bv = *(const float4*)(beta + g0);
  int4   sv = *(const int4*)(sid + g0);
  int4   cv = *(const int4*)(iscp + g0);
  float pm = 0.f, nm = 0.f;
  float bs[4] = {bv.x, bv.y, bv.z, bv.w};
  int   ss[4] = {sv.x, sv.y, sv.z, sv.w};
  int   cs[4] = {cv.x, cv.y, cv.z, cv.w};
  #pragma unroll
  for (int j = 0; j < 4; ++j) {
    float bc = fminf(fmaxf(fixnum(bs[j]), -20.f), 20.f);
    float logit = bc * (1.0f / 0.7f);
    int s = ss[j];
    atomicAdd(&s_cnt[s], 1.0f);
    atomicAdd(&s_den[s], __expf(logit));
    float prob = 1.0f / (1.0f + __expf(-bc));
    if (cs[j] == 1) {
      atomicAdd(&s_cpc[s], 1.0f);
      atomicAdd(&s_cpl[s], logit);
      atomicMin(&s_first[s], h0 + j);
      pm += fmaxf(0.7f - prob, 0.f);
    } else {
      nm += fmaxf(prob - 0.3f, 0.f);
    }
  }
  float pms = blockReduceSum(pm, sred);
  float nms = blockReduceSum(nm, sred);
  if (t == 0) { marg_p[2 * blockIdx.x] = pms; marg_p[2 * blockIdx.x + 1] = nms; }
  __syncthreads();
  size_t base = ((size_t)b * CH + c) * KK;
  for (int k = t; k < KK; k += TPB) {
    cnt_p[base + k] = s_cnt[k]; den_p[base + k] = s_den[k];
    cpc_p[base + k] = s_cpc[k]; cpl_p[base + k] = s_cpl[k];
    first_p[base + k] = s_first[k];
  }
}

__global__ __launch_bounds__(TPB) void k2_fin(
    const float* __restrict__ embed,
    const float* __restrict__ cnt_p, const float* __restrict__ den_p,
    const float* __restrict__ cpc_p, const float* __restrict__ cpl_p,
    const int* __restrict__ first_p,
    float* __restrict__ seg_cnt, float* __restrict__ loss_v,
    float* __restrict__ valid_f, float* __restrict__ has_cp_f,
    float* __restrict__ cpc_tot, float* __restrict__ cp_emb,
    float* __restrict__ d2_acc, float* __restrict__ rep_acc)
{
  int idx = blockIdx.x * TPB + threadIdx.x;
  int b = idx >> 9, k = idx & (KK - 1);
  float cnt = 0.f, den = 0.f, cpc = 0.f, cpl = 0.f;
  int fc = NN;
  #pragma unroll 8
  for (int c = 0; c < CH; ++c) {
    size_t base = ((size_t)b * CH + c) * KK + k;
    cnt += cnt_p[base]; den += den_p[base];
    cpc += cpc_p[base]; cpl += cpl_p[base];
    fc = min(fc, first_p[base]);
  }
  bool present = cnt > 0.f;
  bool vinst = present && (cpc == 1.0f);
  float p = __expf(cpl) / fmaxf(den, 1e-30f);
  seg_cnt[idx] = cnt;
  cpc_tot[idx] = cpc;
  loss_v[idx] = vinst ? -__logf(p + 1e-9f) : 0.f;
  valid_f[idx] = vinst ? 1.f : 0.f;
  has_cp_f[idx] = ((fc < NN) && present) ? 1.f : 0.f;
  d2_acc[idx] = 0.f;
  if (idx < BB) rep_acc[idx] = 0.f;
  int row = fc < NN ? fc : NN - 1;
  const float4* src = (const float4*)(embed + ((size_t)b * NN + row) * DD);
  float4* dst = (float4*)(cp_emb + (size_t)idx * DD);
  #pragma unroll
  for (int q = 0; q < DD / 4; ++q) {
    float4 v = src[q];
    v.x = fixnum(v.x); v.y = fixnum(v.y); v.z = fixnum(v.z); v.w = fixnum(v.w);
    dst[q] = v;
  }
}

__global__ __launch_bounds__(TPB) void k3_attr_rep(
    const float* __restrict__ embed, const int* __restrict__ sid,
    const float* __restrict__ cp_emb, const float* __restrict__ has_cp_f,
    float* __restrict__ d2_acc, float* __restrict__ rep_acc)
{
  __shared__ __align__(16) float s_ce[KK * DD];
  __shared__ float s_tile[64 * 25];
  __shared__ float s_d2[KK];
  int b = blockIdx.x >> 6, c = blockIdx.x & 63, t = threadIdx.x;
  const float4* ceg = (const float4*)(cp_emb + (size_t)b * KK * DD);
  float4* ces = (float4*)s_ce;
  #pragma unroll
  for (int i = 0; i < (KK * DD / 4) / TPB; ++i)
    ces[t + i * TPB] = ceg[t + i * TPB];
  for (int k = t; k < KK; k += TPB) s_d2[k] = 0.f;
  int hl = t >> 2, q = t & 3, d0 = q * 6;
  int rbase = hl * 25 + d0;
  int wI[3];
  #pragma unroll
  for (int j = 0; j < 3; ++j) {
    int f = 2 * (t + j * TPB);
    int h = f / 24;
    wI[j] = h * 25 + (f - h * 24);
  }
  size_t hit0 = (size_t)b * NN + (size_t)c * HPB;
  const float2* eb2 = (const float2*)(embed + hit0 * DD);
  const int* sidb = sid + hit0;
  float2 r[3];
  #pragma unroll
  for (int j = 0; j < 3; ++j) r[j] = eb2[t + j * TPB];
  __syncthreads();
  for (int tile = 0; tile < 16; ++tile) {
    #pragma unroll
    for (int j = 0; j < 3; ++j) {
      s_tile[wI[j]]     = fixnum(r[j].x);
      s_tile[wI[j] + 1] = fixnum(r[j].y);
    }
    __syncthreads();
    if (tile < 15) {
      const float2* nb = eb2 + (size_t)(tile + 1) * (64 * DD / 2);
      #pragma unroll
      for (int j = 0; j < 3; ++j) r[j] = nb[t + j * TPB];
    }
    int s = sidb[tile * 64 + hl];
    int cbase = s * DD + d0;
    float d2 = 0.f;
    #pragma unroll
    for (int d = 0; d < 6; ++d) {
      float x = s_tile[rbase + d] - s_ce[cbase + d];
      d2 += x * x;
    }
    d2 += __shfl_xor(d2, 1, 64);
    d2 += __shfl_xor(d2, 2, 64);
    if (q == 0) atomicAdd(&s_d2[s], fminf(d2, 50.f));
    __syncthreads();
  }
  for (int k = t; k < KK; k += TPB)
    atomicAdd(&d2_acc[b * KK + k], s_d2[k]);
  int j0 = t, j1 = t + TPB;
  float cj0[DD], cj1[DD];
  const float4* cj0p = (const float4*)(s_ce + j0 * DD);
  const float4* cj1p = (const float4*)(s_ce + j1 * DD);
  #pragma unroll
  for (int qq = 0; qq < DD / 4; ++qq) {
    float4 a = cj0p[qq], bq = cj1p[qq];
    cj0[qq*4] = a.x; cj0[qq*4+1] = a.y; cj0[qq*4+2] = a.z; cj0[qq*4+3] = a.w;
    cj1[qq*4] = bq.x; cj1[qq*4+1] = bq.y; cj1[qq*4+2] = bq.z; cj1[qq*4+3] = bq.w;
  }
  float m0 = has_cp_f[b * KK + j0], m1 = has_cp_f[b * KK + j1];
  float acc = 0.f;
  #pragma unroll
  for (int ri = 0; ri < RPB; ++ri) {
    int i = c * RPB + ri;
    float mi = has_cp_f[b * KK + i];
    float d20 = 0.f, d21 = 0.f;
    #pragma unroll
    for (int d = 0; d < DD; ++d) {
      float ci = s_ce[i * DD + d];
      float x0 = ci - cj0[d]; d20 += x0 * x0;
      float x1 = ci - cj1[d]; d21 += x1 * x1;
    }
    acc += mi * (m0 * __expf(-fminf(d20, 50.f)) + m1 * __expf(-fminf(d21, 50.f)));
  }
  float tot = blockReduceSum(acc, s_d2);
  if (t == 0) atomicAdd(&rep_acc[b], tot);
}

__global__ __launch_bounds__(1024) void k4_final(
    const float* __restrict__ d2_acc, const float* __restrict__ seg_cnt,
    const float* __restrict__ loss_v, const float* __restrict__ valid_f,
    const float* __restrict__ cpc_tot, const float* __restrict__ has_cp_f,
    const float* __restrict__ marg_p, const float* __restrict__ rep_acc,
    float* __restrict__ out)
{
  __shared__ float s_b[BB][5];
  int w = threadIdx.x >> 6, l = threadIdx.x & 63;
  int b = w;
  float attr = 0.f, ce = 0.f, vcnt = 0.f, pcnt = 0.f, mcnt = 0.f;
  #pragma unroll
  for (int k = l; k < KK; k += 64) {
    int idx = b * KK + k;
    float hc = has_cp_f[idx];
    attr += hc * (d2_acc[idx] / fmaxf(seg_cnt[idx], 1.f));
    ce   += loss_v[idx];
    vcnt += valid_f[idx];
    pcnt += cpc_tot[idx];
    mcnt += hc;
  }
  float pm = marg_p[(b * CH + l) * 2];
  float nm = marg_p[(b * CH + l) * 2 + 1];
  #pragma unroll
  for (int off = 32; off > 0; off >>= 1) {
    attr += __shfl_down(attr, off, 64);
    ce   += __shfl_down(ce, off, 64);
    vcnt += __shfl_down(vcnt, off, 64);
    pcnt += __shfl_down(pcnt, off, 64);
    mcnt += __shfl_down(mcnt, off, 64);
    pm   += __shfl_down(pm, off, 64);
    nm   += __shfl_down(nm, off, 64);
  }
  if (l == 0) {
    float pos = pcnt, neg = (float)NN - pos;
    float slice_ce = ce / fmaxf(vcnt, 1.f);
    float beta_loss = slice_ce + 5.0f * (pm / fmaxf(pos, 1.f) + nm / fmaxf(neg, 1.f));
    float rep = rep_acc[b] / fmaxf(mcnt * mcnt, 1.f);
    float repulsion = (mcnt > 1.f) ? 1.5f * rep : 0.f;
    float v = (pos >= 1.f && neg >= 1.f && vcnt > 0.f) ? 1.f : 0.f;
    s_b[w][0] = (beta_loss + attr + repulsion) * v;
    s_b[w][1] = beta_loss * v;
    s_b[w][2] = attr * v;
    s_b[w][3] = repulsion * v;
    s_b[w][4] = v;
  }
  __syncthreads();
  if (threadIdx.x == 0) {
    float s0 = 0.f, s1 = 0.f, s2 = 0.f, s3 = 0.f, cv = 0.f;
    #pragma unroll
    for (int i = 0; i < BB; ++i) {
      s0 += s_b[i][0]; s1 += s_b[i][1]; s2 += s_b[i][2]; s3 += s_b[i][3]; cv += s_b[i][4];
    }
    float safe = fmaxf(cv, 1.f);
    bool ok = cv > 0.f;
    out[0] = ok ? s0 / safe : 0.f;
    out[1] = ok ? s1 / safe : 0.f;
    out[2] = ok ? s2 / safe : 0.f;
    out[3] = ok ? s3 / safe : 0.f;
  }
}

extern "C" void kernel_launch(void* const* d_in, const int* in_sizes, int n_in,
                              void* d_out, int out_size, void* d_ws, size_t ws_size,
                              hipStream_t stream) {
  (void)in_sizes; (void)n_in; (void)out_size; (void)ws_size;
  const float* beta  = (const float*)d_in[0];
  const float* embed = (const float*)d_in[1];
  const int*   sid   = (const int*)d_in[2];
  const int*   iscp  = (const int*)d_in[3];
  float* out = (float*)d_out;
  char* ws = (char*)d_ws;

  size_t off = 0;
  auto alloc = [&](size_t bytes) {
    size_t o = off; off += (bytes + 255) & ~(size_t)255; return o;
  };
  // sized for the LARGER (fallback CH=64) layout; fused uses a prefix
  const size_t BCK = (size_t)BB * CH * KK * 4;   // 2 MB partial arrays
  const size_t BKf = (size_t)BB * KK * 4;        // 32 KB
  size_t o_cnt_p  = alloc(BCK);
  size_t o_den_p  = alloc(BCK);
  size_t o_cpc_p  = alloc(BCK);
  size_t o_cpl_p  = alloc(BCK);
  size_t o_first  = alloc(BCK);
  size_t o_marg   = alloc((size_t)BB * CH * 2 * 4);
  size_t o_segc   = alloc(BKf);
  size_t o_lossv  = alloc(BKf);
  size_t o_validf = alloc(BKf);
  size_t o_hascp  = alloc(BKf);
  size_t o_cpct   = alloc(BKf);
  size_t o_d2     = alloc(BKf);
  size_t o_cpe    = alloc((size_t)BB * KK * DD * 4);
  size_t o_rep    = alloc((size_t)BB * 4);

  float* p_cnt  = (float*)(ws + o_cnt_p);
  float* p_den  = (float*)(ws + o_den_p);
  float* p_cpc  = (float*)(ws + o_cpc_p);
  float* p_cpl  = (float*)(ws + o_cpl_p);
  int*   p_fst  = (int*)(ws + o_first);
  float* p_marg = (float*)(ws + o_marg);
  float* p_segc = (float*)(ws + o_segc);
  float* p_lossv= (float*)(ws + o_lossv);
  float* p_vldf = (float*)(ws + o_validf);
  float* p_hcp  = (float*)(ws + o_hascp);
  float* p_cpct = (float*)(ws + o_cpct);
  float* p_d2   = (float*)(ws + o_d2);
  float* p_cpe  = (float*)(ws + o_cpe);
  float* p_rep  = (float*)(ws + o_rep);

  void* args[] = {
    (void*)&beta, (void*)&embed, (void*)&sid, (void*)&iscp,
    (void*)&p_cnt, (void*)&p_den, (void*)&p_cpc, (void*)&p_cpl,
    (void*)&p_fst, (void*)&p_marg, (void*)&p_segc, (void*)&p_lossv,
    (void*)&p_vldf, (void*)&p_hcp, (void*)&p_cpct, (void*)&p_cpe,
    (void*)&p_d2, (void*)&p_rep, (void*)&out
  };
  hipError_t err = hipLaunchCooperativeKernel(
      (const void*)kfused, dim3(FBLK), dim3(FTPB), args, 0, stream);

  if (err != hipSuccess) {
    // Fallback: round-1 verified four-kernel pipeline.
    k1_seg<<<BB * CH, TPB, 0, stream>>>(beta, sid, iscp,
        p_cnt, p_den, p_cpc, p_cpl, p_fst, p_marg);
    k2_fin<<<(BB * KK) / TPB, TPB, 0, stream>>>(embed,
        p_cnt, p_den, p_cpc, p_cpl, p_fst,
        p_segc, p_lossv, p_vldf, p_hcp, p_cpct, p_cpe, p_d2, p_rep);
    k3_attr_rep<<<BB * CH, TPB, 0, stream>>>(embed, sid,
        p_cpe, p_hcp, p_d2, p_rep);
    k4_final<<<1, 1024, 0, stream>>>(p_d2, p_segc, p_lossv, p_vldf,
        p_cpct, p_hcp, p_marg, p_rep, out);
  }
}

// Round 4
// 210.451 us; speedup vs baseline: 1.3670x; 1.3670x over previous
//
#include <hip/hip_runtime.h>
#include <math.h>

#define BB 16
#define NN 65536
#define DD 24
#define KK 512
#define CH 64              // chunks (blocks) per batch for k1/k3
#define HPB (NN / CH)      // 1024 hits per block-chunk
#define TPB 256
#define RPB 8              // repulsion rows per block (CH*RPB == KK)
#define FIRST_INIT 0x7F7F7F7F   // memset byte 0x7F -> 2139062143 > NN

__device__ __forceinline__ float fixnum(float v) {
  return __builtin_isfinite(v) ? v : 0.0f;  // nan_to_num(nan=0, posinf=0, neginf=0)
}

// Full-block (256-thread) sum; returns total in ALL threads.
__device__ __forceinline__ float blockReduceSum(float v, float* sbuf) {
  __syncthreads();
  #pragma unroll
  for (int off = 32; off > 0; off >>= 1) v += __shfl_down(v, off, 64);
  int wid = threadIdx.x >> 6, lane = threadIdx.x & 63;
  if (lane == 0) sbuf[wid] = v;
  __syncthreads();
  return sbuf[0] + sbuf[1] + sbuf[2] + sbuf[3];
}

// ---- K1: per-hit scan -> LDS segment hist -> GLOBAL ATOMIC flush ----
// Accumulators (cnt,den,cpc,cpl,first,marg) pre-zeroed/0x7F by hipMemsetAsync.
__global__ __launch_bounds__(TPB) void k1_seg(
    const float* __restrict__ beta, const int* __restrict__ sid,
    const int* __restrict__ iscp,
    float* __restrict__ cnt_g, float* __restrict__ den_g,
    float* __restrict__ cpc_g, float* __restrict__ cpl_g,
    int* __restrict__ first_g, float* __restrict__ marg_g)
{
  __shared__ float s_cnt[KK], s_den[KK], s_cpc[KK], s_cpl[KK];
  __shared__ int   s_first[KK];
  __shared__ float sred[4];
  int b = blockIdx.x >> 6, c = blockIdx.x & 63, t = threadIdx.x;
  for (int k = t; k < KK; k += TPB) {
    s_cnt[k] = 0.f; s_den[k] = 0.f; s_cpc[k] = 0.f; s_cpl[k] = 0.f; s_first[k] = NN;
  }
  __syncthreads();
  int h0 = c * HPB + t * 4;                 // 4 consecutive hits per thread
  size_t g0 = (size_t)b * NN + h0;
  float4 bv = *(const float4*)(beta + g0);
  int4   sv = *(const int4*)(sid + g0);
  int4   cv = *(const int4*)(iscp + g0);
  float pm = 0.f, nm = 0.f;
  float bs[4] = {bv.x, bv.y, bv.z, bv.w};
  int   ss[4] = {sv.x, sv.y, sv.z, sv.w};
  int   cs[4] = {cv.x, cv.y, cv.z, cv.w};
  #pragma unroll
  for (int j = 0; j < 4; ++j) {
    float bc = fminf(fmaxf(fixnum(bs[j]), -20.f), 20.f);
    float logit = bc * (1.0f / 0.7f);       // TAU
    int s = ss[j];
    atomicAdd(&s_cnt[s], 1.0f);
    atomicAdd(&s_den[s], __expf(logit));    // max-free denom (<=3e14, no overflow)
    float prob = 1.0f / (1.0f + __expf(-bc));
    if (cs[j] == 1) {
      atomicAdd(&s_cpc[s], 1.0f);
      atomicAdd(&s_cpl[s], logit);
      atomicMin(&s_first[s], h0 + j);
      pm += fmaxf(0.7f - prob, 0.f);        // THRESHOLD+MARGIN
    } else {
      nm += fmaxf(prob - 0.3f, 0.f);        // THRESHOLD-MARGIN
    }
  }
  float pms = blockReduceSum(pm, sred);
  float nms = blockReduceSum(nm, sred);
  if (t == 0) {
    if (pms != 0.f) atomicAdd(&marg_g[2 * b], pms);
    if (nms != 0.f) atomicAdd(&marg_g[2 * b + 1], nms);
  }
  __syncthreads();
  int base = b * KK;
  for (int k = t; k < KK; k += TPB) {       // 64-way contention per address
    if (s_cnt[k] != 0.f) {
      atomicAdd(&cnt_g[base + k], s_cnt[k]);
      atomicAdd(&den_g[base + k], s_den[k]);
    }
    if (s_cpc[k] != 0.f) {                  // only chunk 0 typically
      atomicAdd(&cpc_g[base + k], s_cpc[k]);
      atomicAdd(&cpl_g[base + k], s_cpl[k]);
    }
    if (s_first[k] < NN) atomicMin(&first_g[base + k], s_first[k]);
  }
}

// ---- K3: attraction scan (100 MB pass) + fused repulsion ----
// No cp_emb materialization: CP rows gathered directly from embed[first[s]]
// (48 KB hot set per batch, L2-resident). LDS ~10.6 KB -> 8 blocks/CU.
__global__ __launch_bounds__(TPB) void k3_attr_rep(
    const float* __restrict__ embed, const int* __restrict__ sid,
    const int* __restrict__ first_g,
    float* __restrict__ d2_acc, float* __restrict__ rep_acc)
{
  __shared__ float s_tile[64 * 25];               // 6400 B: 64 hits, stride 25
  __shared__ float s_d2[KK];                      // 2048 B: segment accumulators
  __shared__ int   s_first[KK];                   // 2048 B
  __shared__ float sred[4];
  int b = blockIdx.x >> 6, c = blockIdx.x & 63, t = threadIdx.x;

  for (int k = t; k < KK; k += TPB) {
    s_first[k] = first_g[b * KK + k];             // coalesced, L2-hot
    s_d2[k] = 0.f;
  }

  // per-thread constant indices
  int hl = t >> 2, q = t & 3, d0 = q * 6;   // quad: 4 lanes x 6 dims per hit
  int rbase = hl * 25 + d0;                 // LDS read base (tile row)
  int wI[3];                                // LDS write slots (float2 pairs never
  #pragma unroll                            // straddle a 24-float row: f even)
  for (int j = 0; j < 3; ++j) {
    int f = 2 * (t + j * TPB);              // 0..1534
    int h = f / 24;
    wI[j] = h * 25 + (f - h * 24);
  }

  size_t hit0 = (size_t)b * NN + (size_t)c * HPB;
  const float* embB = embed + (size_t)b * NN * DD;
  const float2* eb2 = (const float2*)(embed + hit0 * DD);
  const int* sidb = sid + hit0;

  float2 r[3];                              // preload tile 0
  #pragma unroll
  for (int j = 0; j < 3; ++j) r[j] = eb2[t + j * TPB];
  __syncthreads();                          // s_first, s_d2 ready

  for (int tile = 0; tile < 16; ++tile) {
    #pragma unroll
    for (int j = 0; j < 3; ++j) {           // regs -> LDS (fixnum here)
      s_tile[wI[j]]     = fixnum(r[j].x);
      s_tile[wI[j] + 1] = fixnum(r[j].y);
    }
    __syncthreads();
    if (tile < 15) {                        // prefetch next tile under compute
      const float2* nb = eb2 + (size_t)(tile + 1) * (64 * DD / 2);
      #pragma unroll
      for (int j = 0; j < 3; ++j) r[j] = nb[t + j * TPB];
    }
    int s = sidb[tile * 64 + hl];           // 4 lanes share one addr (merged)
    int fs = s_first[s];
    int row = fs < NN ? fs : 0;             // clamp; masked later by has_cp
    const float2* cep = (const float2*)(embB + (size_t)row * DD + d0);  // 8B-aligned
    float2 c0 = cep[0], c1 = cep[1], c2 = cep[2];   // L1/L2-hot gather
    float ce[6] = {fixnum(c0.x), fixnum(c0.y), fixnum(c1.x),
                   fixnum(c1.y), fixnum(c2.x), fixnum(c2.y)};
    float d2 = 0.f;
    #pragma unroll
    for (int d = 0; d < 6; ++d) {
      float x = s_tile[rbase + d] - ce[d];
      d2 += x * x;
    }
    d2 += __shfl_xor(d2, 1, 64);            // combine quad partials
    d2 += __shfl_xor(d2, 2, 64);
    if (q == 0) atomicAdd(&s_d2[s], fminf(d2, 50.f));
    __syncthreads();                        // reads done before next overwrite
  }

  for (int k = t; k < KK; k += TPB)
    atomicAdd(&d2_acc[b * KK + k], s_d2[k]);   // 64 adds/address device-wide

  // --- repulsion: rows c*RPB..+RPB, cols j0=t, j1=t+TPB (CP rows via embed) ---
  int j0 = t, j1 = t + TPB;
  int f0 = s_first[j0], f1 = s_first[j1];
  float m0 = f0 < NN ? 1.f : 0.f, m1 = f1 < NN ? 1.f : 0.f;
  int r0 = f0 < NN ? f0 : 0, r1 = f1 < NN ? f1 : 0;
  float cj0[DD], cj1[DD];
  const float4* cj0p = (const float4*)(embB + (size_t)r0 * DD);  // 96B rows, 16B-aligned
  const float4* cj1p = (const float4*)(embB + (size_t)r1 * DD);
  #pragma unroll
  for (int qq = 0; qq < DD / 4; ++qq) {
    float4 a = cj0p[qq], bq = cj1p[qq];
    cj0[qq*4]   = fixnum(a.x);  cj0[qq*4+1] = fixnum(a.y);
    cj0[qq*4+2] = fixnum(a.z);  cj0[qq*4+3] = fixnum(a.w);
    cj1[qq*4]   = fixnum(bq.x); cj1[qq*4+1] = fixnum(bq.y);
    cj1[qq*4+2] = fixnum(bq.z); cj1[qq*4+3] = fixnum(bq.w);
  }
  float acc = 0.f;
  #pragma unroll
  for (int ri = 0; ri < RPB; ++ri) {
    int i = c * RPB + ri;
    int fi = s_first[i];                    // uniform
    float mi = fi < NN ? 1.f : 0.f;
    const float* rowp = embB + (size_t)(fi < NN ? fi : 0) * DD;
    float d20 = 0.f, d21 = 0.f;
    #pragma unroll
    for (int d = 0; d < DD; ++d) {
      float ci = fixnum(rowp[d]);           // uniform -> broadcast, L1-hot
      float x0 = ci - cj0[d]; d20 += x0 * x0;
      float x1 = ci - cj1[d]; d21 += x1 * x1;
    }
    acc += mi * (m0 * __expf(-fminf(d20, 50.f)) + m1 * __expf(-fminf(d21, 50.f)));
  }
  float tot = blockReduceSum(acc, sred);
  if (t == 0) atomicAdd(&rep_acc[b], tot);
}

// ---- K4: one block; wave w = batch w; computes CE/margins from raw accums ----
__global__ __launch_bounds__(1024) void k4_final(
    const float* __restrict__ cnt_g, const float* __restrict__ den_g,
    const float* __restrict__ cpc_g, const float* __restrict__ cpl_g,
    const int* __restrict__ first_g, const float* __restrict__ d2_acc,
    const float* __restrict__ marg_g, const float* __restrict__ rep_acc,
    float* __restrict__ out)
{
  __shared__ float s_b[BB][5];
  int w = threadIdx.x >> 6, l = threadIdx.x & 63;   // wave w -> batch w
  int b = w;
  float attr = 0.f, ce = 0.f, vcnt = 0.f, pcnt = 0.f, mcnt = 0.f;
  #pragma unroll
  for (int k = l; k < KK; k += 64) {
    int idx = b * KK + k;
    float cnt = cnt_g[idx], den = den_g[idx];
    float cpc = cpc_g[idx], cpl = cpl_g[idx];
    int   fc  = first_g[idx];
    float d2  = d2_acc[idx];
    bool present = cnt > 0.f;
    bool vinst = present && (cpc == 1.0f);
    float p = __expf(cpl) / fmaxf(den, 1e-30f);
    float hc = (fc < NN) ? 1.f : 0.f;       // first<NN implies present
    ce   += vinst ? -__logf(p + 1e-9f) : 0.f;
    attr += hc * (d2 / fmaxf(cnt, 1.f));
    vcnt += vinst ? 1.f : 0.f;
    pcnt += cpc;
    mcnt += hc;
  }
  #pragma unroll
  for (int off = 32; off > 0; off >>= 1) {
    attr += __shfl_down(attr, off, 64);
    ce   += __shfl_down(ce, off, 64);
    vcnt += __shfl_down(vcnt, off, 64);
    pcnt += __shfl_down(pcnt, off, 64);
    mcnt += __shfl_down(mcnt, off, 64);
  }
  if (l == 0) {
    float pm = marg_g[2 * b], nm = marg_g[2 * b + 1];
    float pos = pcnt, neg = (float)NN - pos;
    float slice_ce = ce / fmaxf(vcnt, 1.f);
    float beta_loss = slice_ce + 5.0f * (pm / fmaxf(pos, 1.f) + nm / fmaxf(neg, 1.f));
    float rep = rep_acc[b] / fmaxf(mcnt * mcnt, 1.f);
    float repulsion = (mcnt > 1.f) ? 1.5f * rep : 0.f;
    float v = (pos >= 1.f && neg >= 1.f && vcnt > 0.f) ? 1.f : 0.f;
    s_b[w][0] = (beta_loss + attr + repulsion) * v;
    s_b[w][1] = beta_loss * v;
    s_b[w][2] = attr * v;
    s_b[w][3] = repulsion * v;
    s_b[w][4] = v;
  }
  __syncthreads();
  if (threadIdx.x == 0) {
    float s0 = 0.f, s1 = 0.f, s2 = 0.f, s3 = 0.f, cv = 0.f;
    #pragma unroll
    for (int i = 0; i < BB; ++i) {
      s0 += s_b[i][0]; s1 += s_b[i][1]; s2 += s_b[i][2]; s3 += s_b[i][3]; cv += s_b[i][4];
    }
    float safe = fmaxf(cv, 1.f);
    bool ok = cv > 0.f;
    out[0] = ok ? s0 / safe : 0.f;
    out[1] = ok ? s1 / safe : 0.f;
    out[2] = ok ? s2 / safe : 0.f;
    out[3] = ok ? s3 / safe : 0.f;
  }
}

extern "C" void kernel_launch(void* const* d_in, const int* in_sizes, int n_in,
                              void* d_out, int out_size, void* d_ws, size_t ws_size,
                              hipStream_t stream) {
  (void)in_sizes; (void)n_in; (void)out_size; (void)ws_size;
  const float* beta  = (const float*)d_in[0];
  const float* embed = (const float*)d_in[1];
  const int*   sid   = (const int*)d_in[2];
  const int*   iscp  = (const int*)d_in[3];
  float* out = (float*)d_out;
  char* ws = (char*)d_ws;

  size_t off = 0;
  auto alloc = [&](size_t bytes) {
    size_t o = off; off += (bytes + 255) & ~(size_t)255; return o;
  };
  const size_t BKf = (size_t)BB * KK * 4;        // 32 KB per accumulator array
  // zero-region (one contiguous memset): cnt, den, cpc, cpl, d2, marg, rep
  size_t o_zero  = alloc(0);
  size_t o_cnt   = alloc(BKf);
  size_t o_den   = alloc(BKf);
  size_t o_cpc   = alloc(BKf);
  size_t o_cpl   = alloc(BKf);
  size_t o_d2    = alloc(BKf);
  size_t o_marg  = alloc((size_t)BB * 2 * 4);
  size_t o_rep   = alloc((size_t)BB * 4);
  size_t zbytes  = off - o_zero;
  size_t o_first = alloc(BKf);                   // memset 0x7F

  float* p_cnt  = (float*)(ws + o_cnt);
  float* p_den  = (float*)(ws + o_den);
  float* p_cpc  = (float*)(ws + o_cpc);
  float* p_cpl  = (float*)(ws + o_cpl);
  float* p_d2   = (float*)(ws + o_d2);
  float* p_marg = (float*)(ws + o_marg);
  float* p_rep  = (float*)(ws + o_rep);
  int*   p_fst  = (int*)(ws + o_first);

  hipMemsetAsync(ws + o_zero, 0, zbytes, stream);
  hipMemsetAsync(ws + o_first, 0x7F, BKf, stream);   // FIRST_INIT > NN

  k1_seg<<<BB * CH, TPB, 0, stream>>>(beta, sid, iscp,
      p_cnt, p_den, p_cpc, p_cpl, p_fst, p_marg);

  k3_attr_rep<<<BB * CH, TPB, 0, stream>>>(embed, sid, p_fst, p_d2, p_rep);

  k4_final<<<1, 1024, 0, stream>>>(p_cnt, p_den, p_cpc, p_cpl,
      p_fst, p_d2, p_marg, p_rep, out);
}

// Round 5
// 207.645 us; speedup vs baseline: 1.3854x; 1.0135x over previous
//
#include <hip/hip_runtime.h>
#include <math.h>

#define BB 16
#define NN 65536
#define DD 24
#define KK 512
#define CH 64              // k1 chunks (blocks) per batch
#define HPB (NN / CH)      // 1024 hits per k1 block
#define TPB 256
// k3 geometry: 2x blocks for occupancy (8 blocks/CU)
#define CH3 128            // k3 chunks per batch
#define HPB3 (NN / CH3)    // 512 hits per k3 block
#define RPB3 4             // repulsion rows per k3 block (CH3*RPB3 == KK)

__device__ __forceinline__ float fixnum(float v) {
  return __builtin_isfinite(v) ? v : 0.0f;  // nan_to_num(nan=0, posinf=0, neginf=0)
}

// Full-block (256-thread) sum; returns total in ALL threads.
__device__ __forceinline__ float blockReduceSum(float v, float* sbuf) {
  __syncthreads();
  #pragma unroll
  for (int off = 32; off > 0; off >>= 1) v += __shfl_down(v, off, 64);
  int wid = threadIdx.x >> 6, lane = threadIdx.x & 63;
  if (lane == 0) sbuf[wid] = v;
  __syncthreads();
  return sbuf[0] + sbuf[1] + sbuf[2] + sbuf[3];
}

// ---- K1: per-hit scan -> LDS segment hist -> GLOBAL ATOMIC flush ----
// Accumulators (cnt,den,cpc,cpl,first,marg) pre-zeroed/0x7F by hipMemsetAsync.
__global__ __launch_bounds__(TPB) void k1_seg(
    const float* __restrict__ beta, const int* __restrict__ sid,
    const int* __restrict__ iscp,
    float* __restrict__ cnt_g, float* __restrict__ den_g,
    float* __restrict__ cpc_g, float* __restrict__ cpl_g,
    int* __restrict__ first_g, float* __restrict__ marg_g)
{
  __shared__ float s_cnt[KK], s_den[KK], s_cpc[KK], s_cpl[KK];
  __shared__ int   s_first[KK];
  __shared__ float sred[4];
  int b = blockIdx.x >> 6, c = blockIdx.x & 63, t = threadIdx.x;
  for (int k = t; k < KK; k += TPB) {
    s_cnt[k] = 0.f; s_den[k] = 0.f; s_cpc[k] = 0.f; s_cpl[k] = 0.f; s_first[k] = NN;
  }
  __syncthreads();
  int h0 = c * HPB + t * 4;                 // 4 consecutive hits per thread
  size_t g0 = (size_t)b * NN + h0;
  float4 bv = *(const float4*)(beta + g0);
  int4   sv = *(const int4*)(sid + g0);
  int4   cv = *(const int4*)(iscp + g0);
  float pm = 0.f, nm = 0.f;
  float bs[4] = {bv.x, bv.y, bv.z, bv.w};
  int   ss[4] = {sv.x, sv.y, sv.z, sv.w};
  int   cs[4] = {cv.x, cv.y, cv.z, cv.w};
  #pragma unroll
  for (int j = 0; j < 4; ++j) {
    float bc = fminf(fmaxf(fixnum(bs[j]), -20.f), 20.f);
    float logit = bc * (1.0f / 0.7f);       // TAU
    int s = ss[j];
    atomicAdd(&s_cnt[s], 1.0f);
    atomicAdd(&s_den[s], __expf(logit));    // max-free denom (<=3e14, no overflow)
    float prob = 1.0f / (1.0f + __expf(-bc));
    if (cs[j] == 1) {
      atomicAdd(&s_cpc[s], 1.0f);
      atomicAdd(&s_cpl[s], logit);
      atomicMin(&s_first[s], h0 + j);
      pm += fmaxf(0.7f - prob, 0.f);        // THRESHOLD+MARGIN
    } else {
      nm += fmaxf(prob - 0.3f, 0.f);        // THRESHOLD-MARGIN
    }
  }
  float pms = blockReduceSum(pm, sred);
  float nms = blockReduceSum(nm, sred);
  if (t == 0) {
    if (pms != 0.f) atomicAdd(&marg_g[2 * b], pms);
    if (nms != 0.f) atomicAdd(&marg_g[2 * b + 1], nms);
  }
  __syncthreads();
  int base = b * KK;
  for (int k = t; k < KK; k += TPB) {       // 64-way contention per address
    if (s_cnt[k] != 0.f) {
      atomicAdd(&cnt_g[base + k], s_cnt[k]);
      atomicAdd(&den_g[base + k], s_den[k]);
    }
    if (s_cpc[k] != 0.f) {                  // only chunk 0 typically
      atomicAdd(&cpc_g[base + k], s_cpc[k]);
      atomicAdd(&cpl_g[base + k], s_cpl[k]);
    }
    if (s_first[k] < NN) atomicMin(&first_g[base + k], s_first[k]);
  }
}

// ---- K3: attraction scan + fused repulsion; latency-optimized ----
// 2048 blocks (8/CU), double-buffered tile (1 barrier/tile), sid staged in
// LDS, CP row for tile t+1 prefetched into registers during tile t.
__global__ __launch_bounds__(TPB) void k3_attr_rep(
    const float* __restrict__ embed, const int* __restrict__ sid,
    const int* __restrict__ first_g,
    float* __restrict__ d2_acc, float* __restrict__ rep_acc)
{
  __shared__ float s_tile[2][64 * 25];            // 12800 B double buffer
  __shared__ float s_d2[KK];                      // 2048 B
  __shared__ int   s_first[KK];                   // 2048 B
  __shared__ int   s_sid[HPB3];                   // 2048 B
  __shared__ float sred[4];
  int b = blockIdx.x >> 7, c = blockIdx.x & 127, t = threadIdx.x;

  size_t hit0 = (size_t)b * NN + (size_t)c * HPB3;
  const float* embB = embed + (size_t)b * NN * DD;
  const float2* eb2 = (const float2*)(embed + hit0 * DD);
  const int* sidb = sid + hit0;

  for (int k = t; k < KK; k += TPB) {
    s_first[k] = first_g[b * KK + k];             // coalesced, L2-hot
    s_d2[k] = 0.f;
  }
  s_sid[t] = sidb[t];                             // 512 sids staged once
  s_sid[t + TPB] = sidb[t + TPB];

  // per-thread constant indices
  int hl = t >> 2, q = t & 3, d0 = q * 6;   // quad: 4 lanes x 6 dims per hit
  int rbase = hl * 25 + d0;                 // LDS read base (tile row)
  int wI[3];                                // LDS write slots (float2 pairs never
  #pragma unroll                            // straddle a 24-float row: f even)
  for (int j = 0; j < 3; ++j) {
    int f = 2 * (t + j * TPB);              // 0..1534
    int h = f / 24;
    wI[j] = h * 25 + (f - h * 24);
  }

  float2 r[3];                              // preload tile 0 (issued pre-sync)
  #pragma unroll
  for (int j = 0; j < 3; ++j) r[j] = eb2[t + j * TPB];
  __syncthreads();                          // s_first, s_sid, s_d2 ready

  // prefetch CP row for tile 0
  int scur = s_sid[hl];
  int fc0 = s_first[scur];
  int rw0 = fc0 < NN ? fc0 : 0;
  const float2* cp0 = (const float2*)(embB + (size_t)rw0 * DD + d0);
  float2 cc0 = cp0[0], cc1 = cp0[1], cc2 = cp0[2];
  #pragma unroll
  for (int j = 0; j < 3; ++j) {             // write buf 0
    s_tile[0][wI[j]]     = fixnum(r[j].x);
    s_tile[0][wI[j] + 1] = fixnum(r[j].y);
  }

  #pragma unroll
  for (int tile = 0; tile < 8; ++tile) {
    __syncthreads();                        // buf[tile&1] visible; prev reads done
    int cur = tile & 1;
    int snext = 0;
    float2 cn0 = {0.f, 0.f}, cn1 = {0.f, 0.f}, cn2 = {0.f, 0.f};
    if (tile < 7) {                         // issue next-tile loads (hidden)
      const float2* nb = eb2 + (size_t)(tile + 1) * (64 * DD / 2);
      r[0] = nb[t]; r[1] = nb[t + TPB]; r[2] = nb[t + 2 * TPB];
      snext = s_sid[(tile + 1) * 64 + hl];
      int fn = s_first[snext];
      int rn = fn < NN ? fn : 0;
      const float2* cpn = (const float2*)(embB + (size_t)rn * DD + d0);
      cn0 = cpn[0]; cn1 = cpn[1]; cn2 = cpn[2];
    }
    float e0 = fixnum(cc0.x), e1 = fixnum(cc0.y), e2 = fixnum(cc1.x),
          e3 = fixnum(cc1.y), e4 = fixnum(cc2.x), e5 = fixnum(cc2.y);
    float d2 = 0.f, x;
    x = s_tile[cur][rbase + 0] - e0; d2 += x * x;
    x = s_tile[cur][rbase + 1] - e1; d2 += x * x;
    x = s_tile[cur][rbase + 2] - e2; d2 += x * x;
    x = s_tile[cur][rbase + 3] - e3; d2 += x * x;
    x = s_tile[cur][rbase + 4] - e4; d2 += x * x;
    x = s_tile[cur][rbase + 5] - e5; d2 += x * x;
    d2 += __shfl_xor(d2, 1, 64);            // combine quad partials
    d2 += __shfl_xor(d2, 2, 64);
    if (q == 0) atomicAdd(&s_d2[scur], fminf(d2, 50.f));
    if (tile < 7) {
      #pragma unroll
      for (int j = 0; j < 3; ++j) {         // write next buffer (waits on loads)
        s_tile[cur ^ 1][wI[j]]     = fixnum(r[j].x);
        s_tile[cur ^ 1][wI[j] + 1] = fixnum(r[j].y);
      }
      scur = snext; cc0 = cn0; cc1 = cn1; cc2 = cn2;
    }
  }
  __syncthreads();                          // last tile's atomics done
  for (int k = t; k < KK; k += TPB)
    if (s_d2[k] != 0.f) atomicAdd(&d2_acc[b * KK + k], s_d2[k]);

  // --- repulsion: rows c*RPB3..+RPB3, cols j0=t, j1=t+TPB (CP via embed) ---
  int j0 = t, j1 = t + TPB;
  int f0 = s_first[j0], f1 = s_first[j1];
  float m0 = f0 < NN ? 1.f : 0.f, m1 = f1 < NN ? 1.f : 0.f;
  int r0 = f0 < NN ? f0 : 0, r1 = f1 < NN ? f1 : 0;
  float cj0[DD], cj1[DD];
  const float4* cj0p = (const float4*)(embB + (size_t)r0 * DD);  // 96B rows
  const float4* cj1p = (const float4*)(embB + (size_t)r1 * DD);
  #pragma unroll
  for (int qq = 0; qq < DD / 4; ++qq) {
    float4 a = cj0p[qq], bq = cj1p[qq];
    cj0[qq*4]   = fixnum(a.x);  cj0[qq*4+1] = fixnum(a.y);
    cj0[qq*4+2] = fixnum(a.z);  cj0[qq*4+3] = fixnum(a.w);
    cj1[qq*4]   = fixnum(bq.x); cj1[qq*4+1] = fixnum(bq.y);
    cj1[qq*4+2] = fixnum(bq.z); cj1[qq*4+3] = fixnum(bq.w);
  }
  float acc = 0.f;
  #pragma unroll
  for (int ri = 0; ri < RPB3; ++ri) {
    int i = c * RPB3 + ri;
    int fi = s_first[i];                    // uniform
    float mi = fi < NN ? 1.f : 0.f;
    const float* rowp = embB + (size_t)(fi < NN ? fi : 0) * DD;
    float d20 = 0.f, d21 = 0.f;
    #pragma unroll
    for (int d = 0; d < DD; ++d) {
      float ci = fixnum(rowp[d]);           // uniform -> broadcast, L1-hot
      float x0 = ci - cj0[d]; d20 += x0 * x0;
      float x1 = ci - cj1[d]; d21 += x1 * x1;
    }
    acc += mi * (m0 * __expf(-fminf(d20, 50.f)) + m1 * __expf(-fminf(d21, 50.f)));
  }
  float tot = blockReduceSum(acc, sred);
  if (t == 0) atomicAdd(&rep_acc[b], tot);
}

// ---- K4: one block; wave w = batch w; computes CE/margins from raw accums ----
__global__ __launch_bounds__(1024) void k4_final(
    const float* __restrict__ cnt_g, const float* __restrict__ den_g,
    const float* __restrict__ cpc_g, const float* __restrict__ cpl_g,
    const int* __restrict__ first_g, const float* __restrict__ d2_acc,
    const float* __restrict__ marg_g, const float* __restrict__ rep_acc,
    float* __restrict__ out)
{
  __shared__ float s_b[BB][5];
  int w = threadIdx.x >> 6, l = threadIdx.x & 63;   // wave w -> batch w
  int b = w;
  float attr = 0.f, ce = 0.f, vcnt = 0.f, pcnt = 0.f, mcnt = 0.f;
  #pragma unroll
  for (int k = l; k < KK; k += 64) {
    int idx = b * KK + k;
    float cnt = cnt_g[idx], den = den_g[idx];
    float cpc = cpc_g[idx], cpl = cpl_g[idx];
    int   fc  = first_g[idx];
    float d2  = d2_acc[idx];
    bool present = cnt > 0.f;
    bool vinst = present && (cpc == 1.0f);
    float p = __expf(cpl) / fmaxf(den, 1e-30f);
    float hc = (fc < NN) ? 1.f : 0.f;       // first<NN implies present
    ce   += vinst ? -__logf(p + 1e-9f) : 0.f;
    attr += hc * (d2 / fmaxf(cnt, 1.f));
    vcnt += vinst ? 1.f : 0.f;
    pcnt += cpc;
    mcnt += hc;
  }
  #pragma unroll
  for (int off = 32; off > 0; off >>= 1) {
    attr += __shfl_down(attr, off, 64);
    ce   += __shfl_down(ce, off, 64);
    vcnt += __shfl_down(vcnt, off, 64);
    pcnt += __shfl_down(pcnt, off, 64);
    mcnt += __shfl_down(mcnt, off, 64);
  }
  if (l == 0) {
    float pm = marg_g[2 * b], nm = marg_g[2 * b + 1];
    float pos = pcnt, neg = (float)NN - pos;
    float slice_ce = ce / fmaxf(vcnt, 1.f);
    float beta_loss = slice_ce + 5.0f * (pm / fmaxf(pos, 1.f) + nm / fmaxf(neg, 1.f));
    float rep = rep_acc[b] / fmaxf(mcnt * mcnt, 1.f);
    float repulsion = (mcnt > 1.f) ? 1.5f * rep : 0.f;
    float v = (pos >= 1.f && neg >= 1.f && vcnt > 0.f) ? 1.f : 0.f;
    s_b[w][0] = (beta_loss + attr + repulsion) * v;
    s_b[w][1] = beta_loss * v;
    s_b[w][2] = attr * v;
    s_b[w][3] = repulsion * v;
    s_b[w][4] = v;
  }
  __syncthreads();
  if (threadIdx.x == 0) {
    float s0 = 0.f, s1 = 0.f, s2 = 0.f, s3 = 0.f, cv = 0.f;
    #pragma unroll
    for (int i = 0; i < BB; ++i) {
      s0 += s_b[i][0]; s1 += s_b[i][1]; s2 += s_b[i][2]; s3 += s_b[i][3]; cv += s_b[i][4];
    }
    float safe = fmaxf(cv, 1.f);
    bool ok = cv > 0.f;
    out[0] = ok ? s0 / safe : 0.f;
    out[1] = ok ? s1 / safe : 0.f;
    out[2] = ok ? s2 / safe : 0.f;
    out[3] = ok ? s3 / safe : 0.f;
  }
}

extern "C" void kernel_launch(void* const* d_in, const int* in_sizes, int n_in,
                              void* d_out, int out_size, void* d_ws, size_t ws_size,
                              hipStream_t stream) {
  (void)in_sizes; (void)n_in; (void)out_size; (void)ws_size;
  const float* beta  = (const float*)d_in[0];
  const float* embed = (const float*)d_in[1];
  const int*   sid   = (const int*)d_in[2];
  const int*   iscp  = (const int*)d_in[3];
  float* out = (float*)d_out;
  char* ws = (char*)d_ws;

  size_t off = 0;
  auto alloc = [&](size_t bytes) {
    size_t o = off; off += (bytes + 255) & ~(size_t)255; return o;
  };
  const size_t BKf = (size_t)BB * KK * 4;        // 32 KB per accumulator array
  // zero-region (one contiguous memset): cnt, den, cpc, cpl, d2, marg, rep
  size_t o_zero  = alloc(0);
  size_t o_cnt   = alloc(BKf);
  size_t o_den   = alloc(BKf);
  size_t o_cpc   = alloc(BKf);
  size_t o_cpl   = alloc(BKf);
  size_t o_d2    = alloc(BKf);
  size_t o_marg  = alloc((size_t)BB * 2 * 4);
  size_t o_rep   = alloc((size_t)BB * 4);
  size_t zbytes  = off - o_zero;
  size_t o_first = alloc(BKf);                   // memset 0x7F -> > NN

  float* p_cnt  = (float*)(ws + o_cnt);
  float* p_den  = (float*)(ws + o_den);
  float* p_cpc  = (float*)(ws + o_cpc);
  float* p_cpl  = (float*)(ws + o_cpl);
  float* p_d2   = (float*)(ws + o_d2);
  float* p_marg = (float*)(ws + o_marg);
  float* p_rep  = (float*)(ws + o_rep);
  int*   p_fst  = (int*)(ws + o_first);

  hipMemsetAsync(ws + o_zero, 0, zbytes, stream);
  hipMemsetAsync(ws + o_first, 0x7F, BKf, stream);

  k1_seg<<<BB * CH, TPB, 0, stream>>>(beta, sid, iscp,
      p_cnt, p_den, p_cpc, p_cpl, p_fst, p_marg);

  k3_attr_rep<<<BB * CH3, TPB, 0, stream>>>(embed, sid, p_fst, p_d2, p_rep);

  k4_final<<<1, 1024, 0, stream>>>(p_cnt, p_den, p_cpc, p_cpl,
      p_fst, p_d2, p_marg, p_rep, out);
}